// Round 1
// baseline (772.165 us; speedup 1.0000x reference)
//
#include <hip/hip_runtime.h>

// QLORA: Y = X @ (W_nf4*c1*c2 + L1@L2)   [fold LoRA into W, one bf16 MFMA GEMM]
// M=8192 (rows of X), K=4096 (D_IN), N=4096 (D_OUT), RANK=16.
// Pipeline per launch:
//   1. cvt_x:  X fp32 -> Xh bf16 (ws)                       [64 MB]
//   2. prep_w: Wt[n][k] = bf16(Wnf4[k][n]*c1*c2[k][n] + sum_r L1[k][r]*L2[r][n])
//              (transposed so GEMM B-fragments are contiguous in K) [32 MB]
//   3. gemm_bt: m97-style 128x128 tile, BK=32, global_load_lds width-16,
//              4 waves x (4x4) v_mfma_f32_16x16x32_bf16, fp32 out.

#define M_ROWS 8192
#define K_DIM  4096
#define N_OUT  4096

typedef float  f32x4  __attribute__((ext_vector_type(4)));
typedef __bf16 bf16x8 __attribute__((ext_vector_type(8)));
typedef unsigned short ushort8v __attribute__((ext_vector_type(8)));

__device__ __forceinline__ unsigned short f32_to_bf16(float f) {
    union { float f; unsigned int u; } v;
    v.f = f;
    unsigned int r = 0x7FFFu + ((v.u >> 16) & 1u);   // round-to-nearest-even
    return (unsigned short)((v.u + r) >> 16);
}

// ---------------------------------------------------------------- X -> bf16
__global__ __launch_bounds__(256) void cvt_x_kernel(const float* __restrict__ X,
                                                    ushort8v* __restrict__ Xh) {
    size_t tid = (size_t)blockIdx.x * 256 + threadIdx.x;   // 8 elems/thread
    const float4* xp = (const float4*)X;
    float4 a = xp[tid * 2];
    float4 b = xp[tid * 2 + 1];
    ushort8v o;
    o[0] = f32_to_bf16(a.x); o[1] = f32_to_bf16(a.y);
    o[2] = f32_to_bf16(a.z); o[3] = f32_to_bf16(a.w);
    o[4] = f32_to_bf16(b.x); o[5] = f32_to_bf16(b.y);
    o[6] = f32_to_bf16(b.z); o[7] = f32_to_bf16(b.w);
    Xh[tid] = o;
}

// ------------------------------------ dequant + LoRA merge + transpose -> bf16
// 64x64 tile per block; coalesced reads along n, coalesced writes along k.
__global__ __launch_bounds__(256) void prep_w_kernel(
        const float* __restrict__ Wnf4, const float* __restrict__ c1p,
        const float* __restrict__ c2,   const float* __restrict__ L1,
        const float* __restrict__ L2,   unsigned short* __restrict__ Wt) {
    __shared__ float tile[64][65];     // +1 pad: conflict-free transpose
    __shared__ float sL2[16][64];      // L2[r][n0+nn]
    const int t  = threadIdx.x;
    const int n0 = blockIdx.x * 64;
    const int k0 = blockIdx.y * 64;
    const float c1 = *c1p;

    // stage the 16x64 slice of L2 for this n-tile
    #pragma unroll
    for (int i = 0; i < 4; ++i) {
        int idx = i * 256 + t;
        sL2[idx >> 6][idx & 63] = L2[(size_t)(idx >> 6) * N_OUT + n0 + (idx & 63)];
    }
    __syncthreads();

    // phase 1: read W row-major (coalesced along n), dequant + LoRA, LDS store
    #pragma unroll
    for (int i = 0; i < 16; ++i) {
        int idx = i * 256 + t;
        int kk = idx >> 6, nn = idx & 63;
        size_t g = (size_t)(k0 + kk) * N_OUT + n0 + nn;
        float v = Wnf4[g] * c1 * c2[g];
        const float* l1 = &L1[(size_t)(k0 + kk) * 16];   // wave-uniform row
        float acc = 0.f;
        #pragma unroll
        for (int r = 0; r < 16; ++r) acc += l1[r] * sL2[r][nn];
        tile[kk][nn] = v + acc;
    }
    __syncthreads();

    // phase 2: write transposed Wt[n][k] (coalesced along k)
    #pragma unroll
    for (int i = 0; i < 16; ++i) {
        int idx = i * 256 + t;
        int nn = idx >> 6, kk = idx & 63;
        Wt[(size_t)(n0 + nn) * K_DIM + k0 + kk] = f32_to_bf16(tile[kk][nn]);
    }
}

// ----------------------------------------------------------------- bf16 GEMM
// C[M][N] = A[M][K] * Bt[N][K]^T ;  128x128 tile, BK=32, 256 threads = 4 waves.
// Wave w owns a 64x64 subtile: 4x4 grid of 16x16x32 MFMAs.
__global__ __launch_bounds__(256) void gemm_bt_kernel(
        const __bf16* __restrict__ A, const __bf16* __restrict__ Bt,
        float* __restrict__ C) {
    __shared__ __bf16 As[128 * 32];   // 8 KB, row-major [row][k], 64 B/row
    __shared__ __bf16 Bs[128 * 32];   // 8 KB

    const int t    = threadIdx.x;
    const int w    = t >> 6;
    const int lane = t & 63;
    const int quad = lane >> 4;
    const int l16  = lane & 15;
    const int m0   = blockIdx.y * 128;
    const int n0   = blockIdx.x * 128;
    const int wm   = (w >> 1) * 64;   // wave's m offset in tile
    const int wn   = (w & 1) * 64;    // wave's n offset in tile

    // per-lane staging source coords: 4 lanes per 64 B row, 16 B each
    const int srow = lane >> 2;        // 0..15
    const int scol = (lane & 3) * 8;   // k offset in elems

    f32x4 acc[4][4] = {};

    for (int kb = 0; kb < K_DIM; kb += 32) {
        __syncthreads();   // previous tile's ds_reads done before overwrite
        // stage A: wave w covers rows [w*32, w*32+32); 2 issues x 1 KB
        #pragma unroll
        for (int j = 0; j < 2; ++j) {
            int row = w * 32 + j * 16 + srow;
            const __bf16* gp = A + (size_t)(m0 + row) * K_DIM + kb + scol;
            __builtin_amdgcn_global_load_lds(
                (const __attribute__((address_space(1))) unsigned int*)gp,
                (__attribute__((address_space(3))) unsigned int*)(As + (w * 32 + j * 16) * 32),
                16, 0, 0);
        }
        #pragma unroll
        for (int j = 0; j < 2; ++j) {
            int row = w * 32 + j * 16 + srow;
            const __bf16* gp = Bt + (size_t)(n0 + row) * K_DIM + kb + scol;
            __builtin_amdgcn_global_load_lds(
                (const __attribute__((address_space(1))) unsigned int*)gp,
                (__attribute__((address_space(3))) unsigned int*)(Bs + (w * 32 + j * 16) * 32),
                16, 0, 0);
        }
        __syncthreads();   // staging drained (compiler emits vmcnt(0))

        bf16x8 af[4], bf[4];
        #pragma unroll
        for (int i = 0; i < 4; ++i)
            af[i] = *(const bf16x8*)(As + (wm + i * 16 + l16) * 32 + quad * 8);
        #pragma unroll
        for (int i = 0; i < 4; ++i)
            bf[i] = *(const bf16x8*)(Bs + (wn + i * 16 + l16) * 32 + quad * 8);

        #pragma unroll
        for (int mt = 0; mt < 4; ++mt)
            #pragma unroll
            for (int nt = 0; nt < 4; ++nt)
                acc[mt][nt] = __builtin_amdgcn_mfma_f32_16x16x32_bf16(
                    af[mt], bf[nt], acc[mt][nt], 0, 0, 0);
    }

    // epilogue: C/D layout col=lane&15, row=quad*4+reg  [m89/m91-verified]
    #pragma unroll
    for (int mt = 0; mt < 4; ++mt) {
        int row = m0 + wm + mt * 16 + quad * 4;
        #pragma unroll
        for (int nt = 0; nt < 4; ++nt) {
            int col = n0 + wn + nt * 16 + l16;
            float* cp = C + (size_t)row * N_OUT + col;
            #pragma unroll
            for (int r = 0; r < 4; ++r)
                cp[(size_t)r * N_OUT] = acc[mt][nt][r];
        }
    }
}

extern "C" void kernel_launch(void* const* d_in, const int* in_sizes, int n_in,
                              void* d_out, int out_size, void* d_ws, size_t ws_size,
                              hipStream_t stream) {
    const float* X    = (const float*)d_in[0];
    const float* Wnf4 = (const float*)d_in[1];
    const float* c1   = (const float*)d_in[2];   // scalar
    const float* c2   = (const float*)d_in[3];
    const float* L1   = (const float*)d_in[4];
    const float* L2   = (const float*)d_in[5];
    float* Y = (float*)d_out;

    // workspace: Xh (M*K bf16 = 64 MB) then Wt (N*K bf16 = 32 MB)
    unsigned short* Xh = (unsigned short*)d_ws;
    unsigned short* Wt = (unsigned short*)((char*)d_ws + (size_t)M_ROWS * K_DIM * 2);

    cvt_x_kernel<<<(M_ROWS * K_DIM / 8 + 255) / 256, 256, 0, stream>>>(X, (ushort8v*)Xh);
    prep_w_kernel<<<dim3(N_OUT / 64, K_DIM / 64), 256, 0, stream>>>(Wnf4, c1, c2, L1, L2, Wt);
    gemm_bt_kernel<<<dim3(N_OUT / 128, M_ROWS / 128), 256, 0, stream>>>(
        (const __bf16*)Xh, (const __bf16*)Wt, Y);
}

// Round 2
// 737.037 us; speedup vs baseline: 1.0477x; 1.0477x over previous
//
#include <hip/hip_runtime.h>

// QLORA: Y = X @ (W_nf4*c1*c2 + L1@L2)   [fold LoRA into W, one bf16 MFMA GEMM]
// M=8192, K=4096, N=4096, RANK=16.
// R2 changes vs R1:
//  - GEMM LDS XOR-swizzle (slot = kg ^ ((row>>1)&3)) applied at the staging
//    *source* (global_load_lds dest is HW-fixed lane*16) and at ds_read —
//    kills the 3.35e7 bank conflicts.
//  - prep_w: float4 W/c2 loads, L1 in LDS, ushort8 16B stores, conflict-free
//    phase-2 read mapping.
//  - native __bf16 casts (RNE) instead of manual rounding.

#define M_ROWS 8192
#define K_DIM  4096
#define N_OUT  4096

typedef float  f32x4  __attribute__((ext_vector_type(4)));
typedef __bf16 bf16x8 __attribute__((ext_vector_type(8)));
typedef unsigned short ushort8v __attribute__((ext_vector_type(8)));

__device__ __forceinline__ unsigned short f2bf(float f) {
    __bf16 h = (__bf16)f;                       // native v_cvt (RNE)
    union { __bf16 h; unsigned short u; } v; v.h = h;
    return v.u;
}

// ---------------------------------------------------------------- X -> bf16
__global__ __launch_bounds__(256) void cvt_x_kernel(const float* __restrict__ X,
                                                    ushort8v* __restrict__ Xh) {
    size_t tid = (size_t)blockIdx.x * 256 + threadIdx.x;   // 8 elems/thread
    const float4* xp = (const float4*)X;
    float4 a = xp[tid * 2];
    float4 b = xp[tid * 2 + 1];
    ushort8v o;
    o[0] = f2bf(a.x); o[1] = f2bf(a.y); o[2] = f2bf(a.z); o[3] = f2bf(a.w);
    o[4] = f2bf(b.x); o[5] = f2bf(b.y); o[6] = f2bf(b.z); o[7] = f2bf(b.w);
    Xh[tid] = o;
}

// ------------------------------------ dequant + LoRA merge + transpose -> bf16
// 64x64 tile per block; float4 reads along n, ushort8 writes along k.
__global__ __launch_bounds__(256) void prep_w_kernel(
        const float* __restrict__ Wnf4, const float* __restrict__ c1p,
        const float* __restrict__ c2,   const float* __restrict__ L1,
        const float* __restrict__ L2,   unsigned short* __restrict__ Wt) {
    __shared__ float tile[64][65];     // +1 pad; scalar access both phases
    __shared__ float sL2[16][64];      // L2[r][n0+nn]
    __shared__ float sL1[64][16];      // L1[k0+kk][r]
    const int t  = threadIdx.x;
    const int n0 = blockIdx.x * 64;
    const int k0 = blockIdx.y * 64;
    const float c1 = *c1p;

    {   // stage L2 slice (16x64) and L1 slice (64x16), float4 each
        int r = t >> 4, c4 = (t & 15) * 4;
        *(float4*)&sL2[r][c4] = *(const float4*)&L2[(size_t)r * N_OUT + n0 + c4];
        int r1 = t >> 2, c1v = (t & 3) * 4;
        *(float4*)&sL1[r1][c1v] = *(const float4*)&L1[(size_t)(k0 + r1) * 16 + c1v];
    }
    __syncthreads();

    // phase 1: float4 along n — dequant + LoRA, store to LDS tile
    #pragma unroll
    for (int i = 0; i < 4; ++i) {
        int idx = i * 1024 + t * 4;
        int kk = idx >> 6, nn = idx & 63;
        size_t g = (size_t)(k0 + kk) * N_OUT + n0 + nn;
        float4 w = *(const float4*)&Wnf4[g];
        float4 s = *(const float4*)&c2[g];
        float o0 = w.x * c1 * s.x, o1 = w.y * c1 * s.y;
        float o2 = w.z * c1 * s.z, o3 = w.w * c1 * s.w;
        #pragma unroll
        for (int r = 0; r < 16; ++r) {
            float a = sL1[kk][r];
            o0 += a * sL2[r][nn];     o1 += a * sL2[r][nn + 1];
            o2 += a * sL2[r][nn + 2]; o3 += a * sL2[r][nn + 3];
        }
        tile[kk][nn] = o0; tile[kk][nn + 1] = o1;
        tile[kk][nn + 2] = o2; tile[kk][nn + 3] = o3;
    }
    __syncthreads();

    // phase 2: thread gathers 8 k's for one n, writes ushort8 (16 B).
    // lanes: kg = t&7, nn = t>>3 -> LDS banks 2-way max; stores 128 B runs.
    #pragma unroll
    for (int i = 0; i < 2; ++i) {
        int task = i * 256 + t;
        int kg = task & 7, nn = task >> 3;
        ushort8v o;
        #pragma unroll
        for (int j = 0; j < 8; ++j) o[j] = f2bf(tile[kg * 8 + j][nn]);
        *(ushort8v*)&Wt[(size_t)(n0 + nn) * K_DIM + k0 + kg * 8] = o;
    }
}

// ----------------------------------------------------------------- bf16 GEMM
// C[M][N] = A[M][K] * Bt[N][K]^T ;  128x128 tile, BK=32, 256 threads = 4 waves.
// LDS layout: row r has 4 slots of 16B; logical k-group kg stored at physical
// slot kg ^ ((r>>1)&3)  -> ds_read_b128 banks spread 2-way max.
__global__ __launch_bounds__(256) void gemm_bt_kernel(
        const __bf16* __restrict__ A, const __bf16* __restrict__ Bt,
        float* __restrict__ C) {
    __shared__ __bf16 As[128 * 32];   // 8 KB
    __shared__ __bf16 Bs[128 * 32];   // 8 KB

    const int t    = threadIdx.x;
    const int w    = t >> 6;
    const int lane = t & 63;
    const int quad = lane >> 4;
    const int l16  = lane & 15;
    const int m0   = blockIdx.y * 128;
    const int n0   = blockIdx.x * 128;
    const int wm   = (w >> 1) * 64;
    const int wn   = (w & 1) * 64;

    // staging: lane l covers LDS offset base + l*16 = row (l>>2), phys slot l&3.
    // logical kg for that slot: (l&3) ^ ((row>>1)&3) = (l&3) ^ ((l>>3)&3).
    const int srow = lane >> 2;
    const int scol = ((lane & 3) ^ ((lane >> 3) & 3)) * 8;   // k offset, elems
    // read-side swizzle term: (row>>1)&3 with row = wm+i*16+l16 -> (l16>>1)&3
    const int rsw = (l16 >> 1) & 3;

    f32x4 acc[4][4] = {};

    for (int kb = 0; kb < K_DIM; kb += 32) {
        __syncthreads();
        #pragma unroll
        for (int j = 0; j < 2; ++j) {
            int row = w * 32 + j * 16 + srow;
            const __bf16* gp = A + (size_t)(m0 + row) * K_DIM + kb + scol;
            __builtin_amdgcn_global_load_lds(
                (const __attribute__((address_space(1))) unsigned int*)gp,
                (__attribute__((address_space(3))) unsigned int*)(As + (w * 32 + j * 16) * 32),
                16, 0, 0);
        }
        #pragma unroll
        for (int j = 0; j < 2; ++j) {
            int row = w * 32 + j * 16 + srow;
            const __bf16* gp = Bt + (size_t)(n0 + row) * K_DIM + kb + scol;
            __builtin_amdgcn_global_load_lds(
                (const __attribute__((address_space(1))) unsigned int*)gp,
                (__attribute__((address_space(3))) unsigned int*)(Bs + (w * 32 + j * 16) * 32),
                16, 0, 0);
        }
        __syncthreads();

        bf16x8 af[4], bf[4];
        #pragma unroll
        for (int i = 0; i < 4; ++i)
            af[i] = *(const bf16x8*)(As + (wm + i * 16 + l16) * 32 + ((quad ^ rsw) * 8));
        #pragma unroll
        for (int i = 0; i < 4; ++i)
            bf[i] = *(const bf16x8*)(Bs + (wn + i * 16 + l16) * 32 + ((quad ^ rsw) * 8));

        #pragma unroll
        for (int mt = 0; mt < 4; ++mt)
            #pragma unroll
            for (int nt = 0; nt < 4; ++nt)
                acc[mt][nt] = __builtin_amdgcn_mfma_f32_16x16x32_bf16(
                    af[mt], bf[nt], acc[mt][nt], 0, 0, 0);
    }

    // epilogue: C/D layout col=lane&15, row=quad*4+reg
    #pragma unroll
    for (int mt = 0; mt < 4; ++mt) {
        int row = m0 + wm + mt * 16 + quad * 4;
        #pragma unroll
        for (int nt = 0; nt < 4; ++nt) {
            int col = n0 + wn + nt * 16 + l16;
            float* cp = C + (size_t)row * N_OUT + col;
            #pragma unroll
            for (int r = 0; r < 4; ++r)
                cp[(size_t)r * N_OUT] = acc[mt][nt][r];
        }
    }
}

extern "C" void kernel_launch(void* const* d_in, const int* in_sizes, int n_in,
                              void* d_out, int out_size, void* d_ws, size_t ws_size,
                              hipStream_t stream) {
    const float* X    = (const float*)d_in[0];
    const float* Wnf4 = (const float*)d_in[1];
    const float* c1   = (const float*)d_in[2];   // scalar
    const float* c2   = (const float*)d_in[3];
    const float* L1   = (const float*)d_in[4];
    const float* L2   = (const float*)d_in[5];
    float* Y = (float*)d_out;

    unsigned short* Xh = (unsigned short*)d_ws;                                  // 64 MB
    unsigned short* Wt = (unsigned short*)((char*)d_ws + (size_t)M_ROWS * K_DIM * 2); // 32 MB

    cvt_x_kernel<<<(M_ROWS * K_DIM / 8 + 255) / 256, 256, 0, stream>>>(X, (ushort8v*)Xh);
    prep_w_kernel<<<dim3(N_OUT / 64, K_DIM / 64), 256, 0, stream>>>(Wnf4, c1, c2, L1, L2, Wt);
    gemm_bt_kernel<<<dim3(N_OUT / 128, M_ROWS / 128), 256, 0, stream>>>(
        (const __bf16*)Xh, (const __bf16*)Wt, Y);
}

// Round 3
// 641.844 us; speedup vs baseline: 1.2030x; 1.1483x over previous
//
#include <hip/hip_runtime.h>

// QLORA: Y = X @ (W_nf4*c1*c2 + L1@L2)   [fold LoRA into W, one bf16 MFMA GEMM]
// M=8192, K=4096, N=4096, RANK=16.
// R3 changes vs R2:
//  - GEMM uses v_mfma_f32_32x32x16_bf16 (2x2 tiles of 32x32 per wave):
//    8 MFMA/k-block instead of 16, faster pipe config (2382 vs 2075 TF ubench).
//    Same XOR swizzle slot^((row>>1)&3) provably conflict-free for the
//    32-row read pattern too; staging code unchanged.
//  - cvt_x and prep_w merged into one dispatch (1D grid split) to drop a
//    launch and sharpen prep-side time attribution.

#define M_ROWS 8192
#define K_DIM  4096
#define N_OUT  4096
#define CVT_BLOCKS 16384        // M*K/8/256
#define PREPW_BLOCKS 4096       // (N/64)*(K/64)

typedef float  f32x16 __attribute__((ext_vector_type(16)));
typedef __bf16 bf16x8 __attribute__((ext_vector_type(8)));
typedef unsigned short ushort8v __attribute__((ext_vector_type(8)));

__device__ __forceinline__ unsigned short f2bf(float f) {
    __bf16 h = (__bf16)f;                       // native v_cvt (RNE)
    union { __bf16 h; unsigned short u; } v; v.h = h;
    return v.u;
}

// ---------------------- merged prep: X->bf16 (blocks < CVT_BLOCKS) + W prep
__global__ __launch_bounds__(256) void prep_kernel(
        const float* __restrict__ X,    ushort8v* __restrict__ Xh,
        const float* __restrict__ Wnf4, const float* __restrict__ c1p,
        const float* __restrict__ c2,   const float* __restrict__ L1,
        const float* __restrict__ L2,   unsigned short* __restrict__ Wt) {
    __shared__ float tile[64][65];
    __shared__ float sL2[16][64];
    __shared__ float sL1[64][16];
    const int t = threadIdx.x;

    if (blockIdx.x < CVT_BLOCKS) {
        // ---- X fp32 -> bf16, 8 elems/thread
        size_t tid = (size_t)blockIdx.x * 256 + t;
        const float4* xp = (const float4*)X;
        float4 a = xp[tid * 2];
        float4 b = xp[tid * 2 + 1];
        ushort8v o;
        o[0] = f2bf(a.x); o[1] = f2bf(a.y); o[2] = f2bf(a.z); o[3] = f2bf(a.w);
        o[4] = f2bf(b.x); o[5] = f2bf(b.y); o[6] = f2bf(b.z); o[7] = f2bf(b.w);
        Xh[tid] = o;
        return;
    }

    // ---- dequant + LoRA merge + transpose, 64x64 tile
    const int wb = blockIdx.x - CVT_BLOCKS;
    const int n0 = (wb & 63) * 64;
    const int k0 = (wb >> 6) * 64;
    const float c1 = *c1p;

    {   // stage L2 (16x64) and L1 (64x16), float4 each
        int r = t >> 4, c4 = (t & 15) * 4;
        *(float4*)&sL2[r][c4] = *(const float4*)&L2[(size_t)r * N_OUT + n0 + c4];
        int r1 = t >> 2, c1v = (t & 3) * 4;
        *(float4*)&sL1[r1][c1v] = *(const float4*)&L1[(size_t)(k0 + r1) * 16 + c1v];
    }
    __syncthreads();

    #pragma unroll
    for (int i = 0; i < 4; ++i) {
        int idx = i * 1024 + t * 4;
        int kk = idx >> 6, nn = idx & 63;
        size_t g = (size_t)(k0 + kk) * N_OUT + n0 + nn;
        float4 w = *(const float4*)&Wnf4[g];
        float4 s = *(const float4*)&c2[g];
        float o0 = w.x * c1 * s.x, o1 = w.y * c1 * s.y;
        float o2 = w.z * c1 * s.z, o3 = w.w * c1 * s.w;
        #pragma unroll
        for (int r = 0; r < 16; ++r) {
            float a = sL1[kk][r];
            o0 += a * sL2[r][nn];     o1 += a * sL2[r][nn + 1];
            o2 += a * sL2[r][nn + 2]; o3 += a * sL2[r][nn + 3];
        }
        tile[kk][nn] = o0; tile[kk][nn + 1] = o1;
        tile[kk][nn + 2] = o2; tile[kk][nn + 3] = o3;
    }
    __syncthreads();

    #pragma unroll
    for (int i = 0; i < 2; ++i) {
        int task = i * 256 + t;
        int kg = task & 7, nn = task >> 3;
        ushort8v o;
        #pragma unroll
        for (int j = 0; j < 8; ++j) o[j] = f2bf(tile[kg * 8 + j][nn]);
        *(ushort8v*)&Wt[(size_t)(n0 + nn) * K_DIM + k0 + kg * 8] = o;
    }
}

// ----------------------------------------------------------------- bf16 GEMM
// C[M][N] = A[M][K] * Bt[N][K]^T ; 128x128 tile, BK=32, 4 waves.
// Wave w: 64x64 subtile as 2x2 grid of 32x32x16 MFMAs.
// LDS: row-major [row][32k], 4x16B slots/row, phys slot = logical ^ ((row>>1)&3).
__global__ __launch_bounds__(256) void gemm_bt_kernel(
        const __bf16* __restrict__ A, const __bf16* __restrict__ Bt,
        float* __restrict__ C) {
    __shared__ __bf16 As[128 * 32];   // 8 KB
    __shared__ __bf16 Bs[128 * 32];   // 8 KB

    const int t    = threadIdx.x;
    const int w    = t >> 6;
    const int lane = t & 63;
    const int half = lane >> 5;       // 0..1
    const int l32  = lane & 31;
    const int m0   = blockIdx.y * 128;
    const int n0   = blockIdx.x * 128;
    const int wm   = (w >> 1) * 64;
    const int wn   = (w & 1) * 64;

    // staging source permutation (same as R2): lane l -> row l>>2,
    // phys slot l&3 holds logical slot (l&3)^((l>>3)&3)
    const int srow = lane >> 2;
    const int scol = ((lane & 3) ^ ((lane >> 3) & 3)) * 8;
    // read-side swizzle: (row>>1)&3 with row = base32 + l32
    const int rsw = (l32 >> 1) & 3;

    f32x16 acc[2][2] = {};

    for (int kb = 0; kb < K_DIM; kb += 32) {
        __syncthreads();
        #pragma unroll
        for (int j = 0; j < 2; ++j) {
            int row = w * 32 + j * 16 + srow;
            const __bf16* gp = A + (size_t)(m0 + row) * K_DIM + kb + scol;
            __builtin_amdgcn_global_load_lds(
                (const __attribute__((address_space(1))) unsigned int*)gp,
                (__attribute__((address_space(3))) unsigned int*)(As + (w * 32 + j * 16) * 32),
                16, 0, 0);
        }
        #pragma unroll
        for (int j = 0; j < 2; ++j) {
            int row = w * 32 + j * 16 + srow;
            const __bf16* gp = Bt + (size_t)(n0 + row) * K_DIM + kb + scol;
            __builtin_amdgcn_global_load_lds(
                (const __attribute__((address_space(1))) unsigned int*)gp,
                (__attribute__((address_space(3))) unsigned int*)(Bs + (w * 32 + j * 16) * 32),
                16, 0, 0);
        }
        __syncthreads();

        bf16x8 af[2][2], bf[2][2];
        #pragma unroll
        for (int mt = 0; mt < 2; ++mt)
            #pragma unroll
            for (int ks = 0; ks < 2; ++ks) {
                int row = wm + mt * 32 + l32;
                int slot = (2 * ks + half) ^ rsw;
                af[mt][ks] = *(const bf16x8*)(As + row * 32 + slot * 8);
            }
        #pragma unroll
        for (int nt = 0; nt < 2; ++nt)
            #pragma unroll
            for (int ks = 0; ks < 2; ++ks) {
                int row = wn + nt * 32 + l32;
                int slot = (2 * ks + half) ^ rsw;
                bf[nt][ks] = *(const bf16x8*)(Bs + row * 32 + slot * 8);
            }

        #pragma unroll
        for (int ks = 0; ks < 2; ++ks)
            #pragma unroll
            for (int mt = 0; mt < 2; ++mt)
                #pragma unroll
                for (int nt = 0; nt < 2; ++nt)
                    acc[mt][nt] = __builtin_amdgcn_mfma_f32_32x32x16_bf16(
                        af[mt][ks], bf[nt][ks], acc[mt][nt], 0, 0, 0);
    }

    // epilogue: C/D 32x32 layout col=lane&31, row=(reg&3)+8*(reg>>2)+4*half
    #pragma unroll
    for (int mt = 0; mt < 2; ++mt)
        #pragma unroll
        for (int nt = 0; nt < 2; ++nt) {
            int col = n0 + wn + nt * 32 + l32;
            #pragma unroll
            for (int reg = 0; reg < 16; ++reg) {
                int row = m0 + wm + mt * 32 + (reg & 3) + 8 * (reg >> 2) + 4 * half;
                C[(size_t)row * N_OUT + col] = acc[mt][nt][reg];
            }
        }
}

extern "C" void kernel_launch(void* const* d_in, const int* in_sizes, int n_in,
                              void* d_out, int out_size, void* d_ws, size_t ws_size,
                              hipStream_t stream) {
    const float* X    = (const float*)d_in[0];
    const float* Wnf4 = (const float*)d_in[1];
    const float* c1   = (const float*)d_in[2];   // scalar
    const float* c2   = (const float*)d_in[3];
    const float* L1   = (const float*)d_in[4];
    const float* L2   = (const float*)d_in[5];
    float* Y = (float*)d_out;

    unsigned short* Xh = (unsigned short*)d_ws;                                       // 64 MB
    unsigned short* Wt = (unsigned short*)((char*)d_ws + (size_t)M_ROWS * K_DIM * 2); // 32 MB

    prep_kernel<<<CVT_BLOCKS + PREPW_BLOCKS, 256, 0, stream>>>(
        X, (ushort8v*)Xh, Wnf4, c1, c2, L1, L2, Wt);
    gemm_bt_kernel<<<dim3(N_OUT / 128, M_ROWS / 128), 256, 0, stream>>>(
        (const __bf16*)Xh, (const __bf16*)Wt, Y);
}